// Round 7
// baseline (222.275 us; speedup 1.0000x reference)
//
#include <hip/hip_runtime.h>

#define DEV __device__ __forceinline__

typedef unsigned short u16;
typedef __attribute__((ext_vector_type(8))) short bf16x8;   // 8 bf16 (4 VGPRs)
typedef __attribute__((ext_vector_type(8))) unsigned short u16x8;
typedef __attribute__((ext_vector_type(4))) float f32x4;

constexpr int Bz = 32, Lz = 1024, Dz = 384, Fz = 384, KWz = 3, Mz = 4096;
constexpr float EPS = 1e-5f;

DEV u16 f2bf(float f) {  // RNE f32 -> bf16
  unsigned u = __float_as_uint(f);
  u += 0x7fffu + ((u >> 16) & 1u);
  return (u16)(u >> 16);
}

typedef __attribute__((address_space(1))) const unsigned char ga_t;
typedef __attribute__((address_space(3))) unsigned char la_t;
DEV void gload16(const void* g, void* l) {
  // async global->LDS, 16B per lane; LDS dest is wave-uniform base + lane*16
  __builtin_amdgcn_global_load_lds((ga_t*)g, (la_t*)l, 16, 0, 0);
}

#define WAITV(n) asm volatile("s_waitcnt vmcnt(" #n ")" ::: "memory")

// ------ prep: weight transpose+cvt, h1 halo zero, cumsum+searchsorted -------
__global__ __launch_bounds__(1024) void k_pre(
    const float* __restrict__ w1, const float* __restrict__ w2,
    u16* __restrict__ w1t, u16* __restrict__ w2t, u16* __restrict__ h1,
    const int* __restrict__ tgt, int* __restrict__ idxb) {
  __shared__ int sc[Lz];
  constexpr int WT = KWz * Fz * Dz;                     // 442368
  constexpr int PREP_ELEMS = 2 * WT + Bz * 2 * Dz;      // 933888
  constexpr int PREP_BLKS = (PREP_ELEMS + 1023) / 1024; // 912
  const int tid = threadIdx.x;

  if (blockIdx.x < PREP_BLKS) {
    int gid = blockIdx.x * 1024 + tid;
    if (gid < WT) {
      int k = gid / (Fz * Dz), rem = gid % (Fz * Dz);
      int f = rem / Dz, d = rem % Dz;
      w1t[gid] = f2bf(w1[(f * Dz + d) * KWz + k]);
    } else if (gid < 2 * WT) {
      int g2 = gid - WT;
      int k = g2 / (Fz * Fz), rem = g2 % (Fz * Fz);
      int co = rem / Fz, ci = rem % Fz;
      w2t[g2] = f2bf(w2[(co * Fz + ci) * KWz + k]);
    } else if (gid < PREP_ELEMS) {
      int p = gid - 2 * WT;  // h1 halo rows
      int b = p / (2 * Dz), r = (p / Dz) & 1, d = p % Dz;
      size_t row = (size_t)b * (Lz + 2) + (r ? (Lz + 1) : 0);
      h1[row * Dz + d] = 0;
    }
    return;
  }
  // ---- cumsum + searchsorted(right) ----
  int b = blockIdx.x - PREP_BLKS;
  sc[tid] = tgt[b * Lz + tid];
  __syncthreads();
  for (int off = 1; off < Lz; off <<= 1) {
    int add = (tid >= off) ? sc[tid - off] : 0;
    __syncthreads();
    sc[tid] += add;
    __syncthreads();
  }
  int total = sc[Lz - 1];
  for (int t = tid; t < Mz; t += 1024) {
    int lo = 0, hi = Lz;
    while (lo < hi) {
      int mid = (lo + hi) >> 1;
      if (sc[mid] > t) hi = mid; else lo = mid + 1;
    }
    int iv = (t < total) ? (lo > Lz - 1 ? Lz - 1 : lo) : -1;
    idxb[b * Mz + t] = iv;
  }
}

// ------------------------------ gather rows ---------------------------------
__global__ void k_gather(const float* __restrict__ x, const int* __restrict__ idxb,
                         float* __restrict__ out) {
  int wid = (blockIdx.x * blockDim.x + threadIdx.x) >> 6;
  int lane = threadIdx.x & 63;
  int nw = (gridDim.x * blockDim.x) >> 6;
  for (int row = wid; row < Bz * Mz; row += nw) {
    int b = row >> 12;  // Mz = 4096
    int iv = idxb[row];
    float4* dst = reinterpret_cast<float4*>(out + (size_t)row * Dz);
    if (iv < 0) {
      float4 z = make_float4(0.f, 0.f, 0.f, 0.f);
      dst[lane] = z;
      if (lane < 32) dst[64 + lane] = z;
    } else {
      const float4* src =
          reinterpret_cast<const float4*>(x + ((size_t)b * Lz + iv) * Dz);
      dst[lane] = src[lane];
      if (lane < 32) dst[64 + lane] = src[64 + lane];
    }
  }
}

// --------- fused conv1d(K=3,'same') + LayerNorm + ReLU (+ final dot) --------
// A: DIRECT global->reg (LAYER1: f32 x + halo clamp + RNE cvt; LAYER2: bf16
// padded h1), 1-step prefetch, ping-pong pend regs. B: 4-buffer LDS with
// counted vmcnt (2.5-step lookahead), 1 barrier/step. Wave tile 64x96.
template <int LAYER>
__global__ __launch_bounds__(512, 2) void k_conv(
    const void* __restrict__ Asrc, // LAYER1: x (f32), LAYER2: h1 (bf16 padded)
    const u16* __restrict__ wt,    // [3][384 out][384 in] bf16
    const float* __restrict__ cbias,
    const float* __restrict__ lng, const float* __restrict__ lnb,
    u16* __restrict__ hout,        // LAYER==1: padded output buffer
    const float* __restrict__ lw, const float* __restrict__ lbias,
    float* __restrict__ dur)       // LAYER==2: [B*L]
{
  __shared__ __align__(16) u16 Bsh[4][384 * 32];   // 4 x 24KB
  __shared__ float s_sum[4][128], s_sq[4][128], s_dot[4][128];

  const int tid = threadIdx.x;
  const int lane = tid & 63, wave = tid >> 6;   // 8 waves
  const int wr = wave >> 2, wc = wave & 3;      // 2 x 4 wave grid
  const int l15 = lane & 15, lh = lane >> 4;
  const int lh8 = lh * 8;
  const int b = blockIdx.x >> 3, l0 = (blockIdx.x & 7) << 7;

  // ---- B staging: 24 chunks of 1KB, wave w takes chunks w, w+8, w+16 ------
  int gof[3], ldo[3];
  #pragma unroll
  for (int i = 0; i < 3; ++i) {
    int c = wave + 8 * i;
    int slot = c * 64 + lane, f = slot >> 2, q = slot & 3;
    int ks = q ^ ((f >> 1) & 3);             // XOR slot swizzle (involution)
    gof[i] = f * 384 + ks * 8;
    ldo[i] = c * 512;
  }
  auto STAGE = [&](int kt, int buf) {
    int tap = kt / 12;
    int d0 = (kt - tap * 12) * 32;
    const u16* sb = wt + tap * (384 * 384) + d0;
    #pragma unroll
    for (int i = 0; i < 3; ++i) gload16(sb + gof[i], &Bsh[buf][ldo[i]]);
  };

  // ---- A direct-load state ----
  const float* xb = (const float*)Asrc + (size_t)b * Lz * 384;  // LAYER1
  int arow[4];
  const u16* Pm[4];                                             // LAYER2
  #pragma unroll
  for (int m = 0; m < 4; ++m) {
    int rel = wr * 64 + m * 16 + l15;
    arow[m] = l0 + rel;
    Pm[m] = (const u16*)Asrc +
            ((size_t)(b * (Lz + 2) + l0 + rel)) * 384 + lh8;
  }
  float4 pLo[2][4], pHi[2][4];  // LAYER1 pend (literal-indexed only)
  bf16x8 pB[2][4];              // LAYER2 pend

  auto AISSUE1 = [&](int kt, float4 (&lo)[4], float4 (&hi)[4]) {
    int tap = kt / 12, d0 = (kt - tap * 12) * 32;
    #pragma unroll
    for (int m = 0; m < 4; ++m) {
      int q = arow[m] + tap - 1;
      int qc = q < 0 ? 0 : (q > Lz - 1 ? Lz - 1 : q);
      const float* p = xb + (size_t)qc * 384 + d0 + lh8;
      float4 a = *reinterpret_cast<const float4*>(p);
      float4 c = *reinterpret_cast<const float4*>(p + 4);
      if (q != qc) { a = make_float4(0.f, 0.f, 0.f, 0.f); c = a; }
      lo[m] = a; hi[m] = c;
    }
  };
  auto AISSUE2 = [&](int kt, bf16x8 (&pb)[4]) {
    int tap = kt / 12, d0 = (kt - tap * 12) * 32;
    int off = tap * 384 + d0;
    #pragma unroll
    for (int m = 0; m < 4; ++m)
      pb[m] = *reinterpret_cast<const bf16x8*>(Pm[m] + off);
  };

  // ---- fragment read offsets for B (u16 units), swizzle matches staging ----
  int boff[6];
  #pragma unroll
  for (int n = 0; n < 6; ++n) {
    int c = wc * 96 + n * 16 + l15;
    boff[n] = c * 32 + (lh ^ ((c >> 1) & 3)) * 8;
  }

  f32x4 acc[4][6] = {};

  // prologue: queue order Bst0, Bst1, av0, Bst2
  STAGE(0, 0);
  STAGE(1, 1);
  if constexpr (LAYER == 1) AISSUE1(0, pLo[0], pHi[0]);
  else                      AISSUE2(0, pB[0]);
  STAGE(2, 2);

#define PHASE(KT, U, V)                                                        \
  {                                                                            \
    const int kt = (KT);                                                       \
    if constexpr (LAYER == 1) {                                                \
      if (kt < 34) WAITV(14); else if (kt == 34) WAITV(11); else WAITV(8);     \
    } else {                                                                   \
      if (kt < 34) WAITV(10); else if (kt == 34) WAITV(7); else WAITV(4);      \
    }                                                                          \
    __builtin_amdgcn_s_barrier();                                              \
    __builtin_amdgcn_sched_barrier(0);                                         \
    if (kt < 35) {                                                             \
      if constexpr (LAYER == 1) AISSUE1(kt + 1, pLo[V], pHi[V]);               \
      else                      AISSUE2(kt + 1, pB[V]);                        \
    }                                                                          \
    if (kt <= 32) STAGE(kt + 3, (kt + 3) & 3);                                 \
    __builtin_amdgcn_sched_barrier(0);                                         \
    bf16x8 av[4];                                                              \
    if constexpr (LAYER == 1) {                                                \
      _Pragma("unroll")                                                        \
      for (int m = 0; m < 4; ++m) {                                            \
        u16x8 f;                                                               \
        f[0] = f2bf(pLo[U][m].x); f[1] = f2bf(pLo[U][m].y);                    \
        f[2] = f2bf(pLo[U][m].z); f[3] = f2bf(pLo[U][m].w);                    \
        f[4] = f2bf(pHi[U][m].x); f[5] = f2bf(pHi[U][m].y);                    \
        f[6] = f2bf(pHi[U][m].z); f[7] = f2bf(pHi[U][m].w);                    \
        av[m] = (bf16x8)f;                                                     \
      }                                                                        \
    } else {                                                                   \
      _Pragma("unroll")                                                        \
      for (int m = 0; m < 4; ++m) av[m] = pB[U][m];                            \
    }                                                                          \
    bf16x8 bv[6];                                                              \
    _Pragma("unroll")                                                          \
    for (int n = 0; n < 6; ++n)                                                \
      bv[n] = *reinterpret_cast<const bf16x8*>(&Bsh[kt & 3][boff[n]]);         \
    _Pragma("unroll")                                                          \
    for (int m = 0; m < 4; ++m)                                                \
      _Pragma("unroll")                                                        \
      for (int n = 0; n < 6; ++n)                                              \
        acc[m][n] = __builtin_amdgcn_mfma_f32_16x16x32_bf16(av[m], bv[n],      \
                                                            acc[m][n], 0, 0, 0);\
  }

  for (int k2 = 0; k2 < 18; ++k2) {
    PHASE(2 * k2, 0, 1);
    PHASE(2 * k2 + 1, 1, 0);
  }
#undef PHASE

  // ---- epilogue: bias + LayerNorm(F) + ReLU, then store bf16 or dot(lw) ----
  __syncthreads();
  float gv[6], bvv[6], cbv[6], lwv[6];
  #pragma unroll
  for (int n = 0; n < 6; ++n) {
    int c = wc * 96 + n * 16 + l15;
    gv[n] = lng[c]; bvv[n] = lnb[c]; cbv[n] = cbias[c];
    lwv[n] = (LAYER == 2) ? lw[c] : 0.f;
  }
  #pragma unroll
  for (int m = 0; m < 4; ++m) {
    #pragma unroll
    for (int r = 0; r < 4; ++r) {
      float s = 0.f, q2 = 0.f;
      #pragma unroll
      for (int n = 0; n < 6; ++n) {
        float v = acc[m][n][r] + cbv[n];
        s += v; q2 += v * v;
      }
      #pragma unroll
      for (int off = 1; off < 16; off <<= 1) {
        s += __shfl_xor(s, off);
        q2 += __shfl_xor(q2, off);
      }
      if (l15 == 0) {
        int row = wr * 64 + m * 16 + lh * 4 + r;
        s_sum[wc][row] = s;
        s_sq[wc][row] = q2;
      }
    }
  }
  __syncthreads();
  #pragma unroll
  for (int m = 0; m < 4; ++m) {
    #pragma unroll
    for (int r = 0; r < 4; ++r) {
      int row = wr * 64 + m * 16 + lh * 4 + r;
      float S = 0.f, Q = 0.f;
      #pragma unroll
      for (int w = 0; w < 4; ++w) { S += s_sum[w][row]; Q += s_sq[w][row]; }
      float mean = S * (1.f / 384.f);
      float var = Q * (1.f / 384.f) - mean * mean;
      float rstd = rsqrtf(var + EPS);
      float dotp = 0.f;
      #pragma unroll
      for (int n = 0; n < 6; ++n) {
        float v = acc[m][n][r] + cbv[n];
        float y = fmaxf((v - mean) * rstd * gv[n] + bvv[n], 0.f);
        if constexpr (LAYER == 1) {
          int c = wc * 96 + n * 16 + l15;
          hout[((size_t)(b * (Lz + 2) + l0 + row + 1)) * 384 + c] = f2bf(y);
        } else {
          dotp += y * lwv[n];
        }
      }
      if constexpr (LAYER == 2) {
        #pragma unroll
        for (int off = 1; off < 16; off <<= 1) dotp += __shfl_xor(dotp, off);
        if (l15 == 0) s_dot[wc][row] = dotp;
      }
    }
  }
  if constexpr (LAYER == 2) {
    __syncthreads();
    if (tid < 128) {
      float dsum = lbias[0];
      #pragma unroll
      for (int w = 0; w < 4; ++w) dsum += s_dot[w][tid];
      dur[(size_t)b * Lz + l0 + tid] = fmaxf(dsum, 0.f);
    }
  }
}

extern "C" void kernel_launch(void* const* d_in, const int* in_sizes, int n_in,
                              void* d_out, int out_size, void* d_ws, size_t ws_size,
                              hipStream_t stream) {
  (void)in_sizes; (void)n_in; (void)out_size; (void)ws_size;
  const float* x   = (const float*)d_in[0];
  const int* tgt   = (const int*)d_in[1];
  const float* w1  = (const float*)d_in[3];
  const float* c1b = (const float*)d_in[4];
  const float* g1  = (const float*)d_in[5];
  const float* b1  = (const float*)d_in[6];
  const float* w2  = (const float*)d_in[7];
  const float* c2b = (const float*)d_in[8];
  const float* g2  = (const float*)d_in[9];
  const float* b2  = (const float*)d_in[10];
  const float* lw  = (const float*)d_in[11];
  const float* lb  = (const float*)d_in[12];

  float* out0 = (float*)d_out;
  float* dur  = out0 + (size_t)Bz * Mz * Dz;

  const size_t h1_n = (size_t)Bz * (Lz + 2) * Dz;  // 12,607,488 bf16
  const size_t wt_n = (size_t)KWz * Fz * Dz;       // 442,368 bf16
  u16* h1  = (u16*)d_ws;
  u16* w1t = h1 + h1_n;
  u16* w2t = w1t + wt_n;
  int* idxb = (int*)(w2t + wt_n);  // byte offset divisible by 4

  constexpr int PREP_BLKS =
      (2 * KWz * Fz * Dz + Bz * 2 * Dz + 1023) / 1024;  // 912
  k_pre<<<PREP_BLKS + Bz, 1024, 0, stream>>>(w1, w2, w1t, w2t, h1, tgt, idxb);
  k_conv<1><<<256, 512, 0, stream>>>(x, w1t, c1b, g1, b1, h1, nullptr, nullptr,
                                     nullptr);
  k_conv<2><<<256, 512, 0, stream>>>(h1, w2t, c2b, g2, b2, nullptr, lw, lb, dur);
  k_gather<<<2048, 256, 0, stream>>>(x, idxb, out0);
}

// Round 8
// 173.861 us; speedup vs baseline: 1.2785x; 1.2785x over previous
//
#include <hip/hip_runtime.h>

#define DEV __device__ __forceinline__

typedef unsigned short u16;
typedef __attribute__((ext_vector_type(8))) short bf16x8;   // 8 bf16 (4 VGPRs)
typedef __attribute__((ext_vector_type(8))) unsigned short u16x8;
typedef __attribute__((ext_vector_type(4))) float f32x4;

constexpr int Bz = 32, Lz = 1024, Dz = 384, Fz = 384, KWz = 3, Mz = 4096;
constexpr float EPS = 1e-5f;

DEV u16 f2bf(float f) {  // RNE f32 -> bf16
  unsigned u = __float_as_uint(f);
  u += 0x7fffu + ((u >> 16) & 1u);
  return (u16)(u >> 16);
}

typedef __attribute__((address_space(1))) const unsigned char ga_t;
typedef __attribute__((address_space(3))) unsigned char la_t;
DEV void gload16(const void* g, void* l) {
  // async global->LDS, 16B per lane; LDS dest is wave-uniform base + lane*16
  __builtin_amdgcn_global_load_lds((ga_t*)g, (la_t*)l, 16, 0, 0);
}

// -- fused: convert x -> padded bf16, weight prep, halo zero, cumsum+search --
__global__ __launch_bounds__(1024) void k_pre(
    const float* __restrict__ x, u16* __restrict__ xbf,
    const float* __restrict__ w1, const float* __restrict__ w2,
    u16* __restrict__ w1t, u16* __restrict__ w2t, u16* __restrict__ h1,
    const int* __restrict__ tgt, int* __restrict__ idxb) {
  __shared__ int sc[Lz];
  constexpr int CONV_BLKS = (Bz * Lz * Dz / 8) / 1024;   // 1536
  constexpr int WT = KWz * Fz * Dz;                      // 442368
  constexpr int PREP_ELEMS = 2 * WT + 2 * Bz * 2 * Dz;   // 933888
  constexpr int PREP_BLKS = (PREP_ELEMS + 1023) / 1024;  // 912
  const int tid = threadIdx.x;

  if (blockIdx.x < CONV_BLKS) {  // ---- x f32 -> bf16, padded rows ----
    int gid = blockIdx.x * 1024 + tid;
    size_t e = (size_t)gid * 8;
    float4 v0 = *reinterpret_cast<const float4*>(x + e);
    float4 v1 = *reinterpret_cast<const float4*>(x + e + 4);
    int d = (int)(e % Dz);               // 8 | 384 -> never crosses a row
    int l = (int)((e / Dz) % Lz);
    int b = (int)(e / ((size_t)Dz * Lz));
    u16x8 u;
    u[0] = f2bf(v0.x); u[1] = f2bf(v0.y); u[2] = f2bf(v0.z); u[3] = f2bf(v0.w);
    u[4] = f2bf(v1.x); u[5] = f2bf(v1.y); u[6] = f2bf(v1.z); u[7] = f2bf(v1.w);
    *reinterpret_cast<u16x8*>(xbf + ((size_t)(b * (Lz + 2) + l + 1)) * Dz + d) = u;
    return;
  }
  if (blockIdx.x < CONV_BLKS + PREP_BLKS) {  // ---- weights + halos ----
    int gid = (blockIdx.x - CONV_BLKS) * 1024 + tid;
    if (gid < WT) {
      int k = gid / (Fz * Dz), rem = gid % (Fz * Dz);
      int f = rem / Dz, d = rem % Dz;
      w1t[gid] = f2bf(w1[(f * Dz + d) * KWz + k]);
    } else if (gid < 2 * WT) {
      int g2 = gid - WT;
      int k = g2 / (Fz * Fz), rem = g2 % (Fz * Fz);
      int co = rem / Fz, ci = rem % Fz;
      w2t[g2] = f2bf(w2[(co * Fz + ci) * KWz + k]);
    } else if (gid < PREP_ELEMS) {
      int p = gid - 2 * WT;
      u16* buf = (p < Bz * 2 * Dz) ? xbf : h1;
      int q = p % (Bz * 2 * Dz);
      int b = q / (2 * Dz), r = (q / Dz) & 1, d = q % Dz;
      size_t row = (size_t)b * (Lz + 2) + (r ? (Lz + 1) : 0);
      buf[row * Dz + d] = 0;
    }
    return;
  }
  // ---- cumsum + searchsorted(right) ----
  int b = blockIdx.x - CONV_BLKS - PREP_BLKS;
  sc[tid] = tgt[b * Lz + tid];
  __syncthreads();
  for (int off = 1; off < Lz; off <<= 1) {
    int add = (tid >= off) ? sc[tid - off] : 0;
    __syncthreads();
    sc[tid] += add;
    __syncthreads();
  }
  int total = sc[Lz - 1];
  for (int t = tid; t < Mz; t += 1024) {
    int lo = 0, hi = Lz;
    while (lo < hi) {
      int mid = (lo + hi) >> 1;
      if (sc[mid] > t) hi = mid; else lo = mid + 1;
    }
    int iv = (t < total) ? (lo > Lz - 1 ? Lz - 1 : lo) : -1;
    idxb[b * Mz + t] = iv;
  }
}

// ------------------------------ gather rows ---------------------------------
__global__ void k_gather(const float* __restrict__ x, const int* __restrict__ idxb,
                         float* __restrict__ out) {
  int wid = (blockIdx.x * blockDim.x + threadIdx.x) >> 6;
  int lane = threadIdx.x & 63;
  int nw = (gridDim.x * blockDim.x) >> 6;
  for (int row = wid; row < Bz * Mz; row += nw) {
    int b = row >> 12;  // Mz = 4096
    int iv = idxb[row];
    float4* dst = reinterpret_cast<float4*>(out + (size_t)row * Dz);
    if (iv < 0) {
      float4 z = make_float4(0.f, 0.f, 0.f, 0.f);
      dst[lane] = z;
      if (lane < 32) dst[64 + lane] = z;
    } else {
      const float4* src =
          reinterpret_cast<const float4*>(x + ((size_t)b * Lz + iv) * Dz);
      dst[lane] = src[lane];
      if (lane < 32) dst[64 + lane] = src[64 + lane];
    }
  }
}

// --------- fused conv1d(K=3,'same') + LayerNorm + ReLU (+ final dot) --------
// GEMM tile: [128 rows] x [384 cols], K = 36 steps of 32. 8 waves (2x4), wave
// tile 64x96. A: bf16 direct global->reg from padded buffer (depth-1 reg
// prefetch, no LDS). B: triple-buffered LDS via global_load_lds, depth-2,
// counted vmcnt + raw s_barrier (T3+T4). LDS/step 72KB < MFMA 931cy.
template <int LAYER>
__global__ __launch_bounds__(512, 2) void k_conv(
    const u16* __restrict__ in,    // [Bz][Lz+2][384] bf16 (halo-padded)
    const u16* __restrict__ wt,    // [3][384 out][384 in] bf16
    const float* __restrict__ cbias,
    const float* __restrict__ lng, const float* __restrict__ lnb,
    u16* __restrict__ hout,        // LAYER==1: padded output buffer
    const float* __restrict__ lw, const float* __restrict__ lbias,
    float* __restrict__ dur)       // LAYER==2: [B*L]
{
  __shared__ __align__(16) u16 Bsh[3][384 * 32];   // 3 x 24KB
  __shared__ float s_sum[4][128], s_sq[4][128], s_dot[4][128];

  const int tid = threadIdx.x;
  const int lane = tid & 63, wave = tid >> 6;   // 8 waves
  const int wr = wave >> 2, wc = wave & 3;      // 2 x 4 wave grid
  const int l15 = lane & 15, lh = lane >> 4;
  const int b = blockIdx.x >> 3, l0 = (blockIdx.x & 7) << 7;

  // ---- B staging: 24 chunks of 1KB, wave w takes chunks w, w+8, w+16 ------
  int gof[3], ldo[3];
  #pragma unroll
  for (int i = 0; i < 3; ++i) {
    int c = wave + 8 * i;
    int slot = c * 64 + lane, f = slot >> 2, q = slot & 3;
    int ks = q ^ ((f >> 1) & 3);             // XOR slot swizzle (involution)
    gof[i] = f * 384 + ks * 8;
    ldo[i] = c * 512;
  }
  auto STAGE = [&](int kt, int buf) {
    int tap = kt / 12;
    int d0 = (kt - tap * 12) * 32;
    const u16* sb = wt + tap * (384 * 384) + d0;
    #pragma unroll
    for (int i = 0; i < 3; ++i) gload16(sb + gof[i], &Bsh[buf][ldo[i]]);
  };

  // ---- A direct-to-reg: padded bf16 rows, 16B per lane per m -------------
  const u16* Pm[4];
  #pragma unroll
  for (int m = 0; m < 4; ++m) {
    int rel = wr * 64 + m * 16 + l15;
    Pm[m] = in + ((size_t)(b * (Lz + 2) + l0 + rel)) * 384 + lh * 8;
  }
  bf16x8 pA[2][4];  // ping-pong pend regs (literal-indexed only)
  auto AISSUE = [&](int kt, bf16x8 (&pa)[4]) {
    int tap = kt / 12, d0 = (kt - tap * 12) * 32;
    int off = tap * 384 + d0;  // padded row shift by tap + col window
    #pragma unroll
    for (int m = 0; m < 4; ++m)
      pa[m] = *reinterpret_cast<const bf16x8*>(Pm[m] + off);
  };

  // ---- B fragment read offsets (u16 units), swizzle matches staging -------
  int boff[6];
  #pragma unroll
  for (int n = 0; n < 6; ++n) {
    int c = wc * 96 + n * 16 + l15;
    boff[n] = c * 32 + (lh ^ ((c >> 1) & 3)) * 8;
  }

  f32x4 acc[4][6] = {};

  // prologue: B(0),B(1),A(0),B(2) — kt=0 waits vmcnt(3) (reorder-safe)
  STAGE(0, 0);
  STAGE(1, 1);
  AISSUE(0, pA[0]);
  STAGE(2, 2);

#define PHASE(KT, U, V)                                                        \
  {                                                                            \
    const int kt = (KT);                                                       \
    if (kt == 0)       asm volatile("s_waitcnt vmcnt(3)" ::: "memory");        \
    else if (kt < 35)  asm volatile("s_waitcnt vmcnt(7)" ::: "memory");        \
    else               asm volatile("s_waitcnt vmcnt(4)" ::: "memory");        \
    __builtin_amdgcn_s_barrier();                                              \
    __builtin_amdgcn_sched_barrier(0);                                         \
    if (kt < 35) AISSUE(kt + 1, pA[V]);                                        \
    if (kt < 34) {                                                             \
      int nb = (kt + 3) % 3; /* kt+2 maps to buf (kt+2)%3 */                   \
      nb = (kt + 2) % 3;                                                       \
      STAGE(kt + 2, nb);                                                       \
    }                                                                          \
    bf16x8 bv[6];                                                              \
    _Pragma("unroll")                                                          \
    for (int n = 0; n < 6; ++n)                                                \
      bv[n] = *reinterpret_cast<const bf16x8*>(&Bsh[kt % 3][boff[n]]);         \
    _Pragma("unroll")                                                          \
    for (int m = 0; m < 4; ++m)                                                \
      _Pragma("unroll")                                                        \
      for (int n = 0; n < 6; ++n)                                              \
        acc[m][n] = __builtin_amdgcn_mfma_f32_16x16x32_bf16(pA[U][m], bv[n],   \
                                                            acc[m][n], 0, 0, 0);\
  }

  for (int k2 = 0; k2 < 18; ++k2) {
    PHASE(2 * k2, 0, 1);
    PHASE(2 * k2 + 1, 1, 0);
  }
#undef PHASE

  // ---- epilogue: bias + LayerNorm(F) + ReLU, then store bf16 or dot(lw) ----
  __syncthreads();
  float gv[6], bvv[6], cbv[6], lwv[6];
  #pragma unroll
  for (int n = 0; n < 6; ++n) {
    int c = wc * 96 + n * 16 + l15;
    gv[n] = lng[c]; bvv[n] = lnb[c]; cbv[n] = cbias[c];
    lwv[n] = (LAYER == 2) ? lw[c] : 0.f;
  }
  #pragma unroll
  for (int m = 0; m < 4; ++m) {
    #pragma unroll
    for (int r = 0; r < 4; ++r) {
      float s = 0.f, q2 = 0.f;
      #pragma unroll
      for (int n = 0; n < 6; ++n) {
        float v = acc[m][n][r] + cbv[n];
        s += v; q2 += v * v;
      }
      #pragma unroll
      for (int off = 1; off < 16; off <<= 1) {
        s += __shfl_xor(s, off);
        q2 += __shfl_xor(q2, off);
      }
      if (l15 == 0) {
        int row = wr * 64 + m * 16 + lh * 4 + r;
        s_sum[wc][row] = s;
        s_sq[wc][row] = q2;
      }
    }
  }
  __syncthreads();
  #pragma unroll
  for (int m = 0; m < 4; ++m) {
    #pragma unroll
    for (int r = 0; r < 4; ++r) {
      int row = wr * 64 + m * 16 + lh * 4 + r;
      float S = 0.f, Q = 0.f;
      #pragma unroll
      for (int w = 0; w < 4; ++w) { S += s_sum[w][row]; Q += s_sq[w][row]; }
      float mean = S * (1.f / 384.f);
      float var = Q * (1.f / 384.f) - mean * mean;
      float rstd = rsqrtf(var + EPS);
      float dotp = 0.f;
      #pragma unroll
      for (int n = 0; n < 6; ++n) {
        float v = acc[m][n][r] + cbv[n];
        float y = fmaxf((v - mean) * rstd * gv[n] + bvv[n], 0.f);
        if constexpr (LAYER == 1) {
          int c = wc * 96 + n * 16 + l15;
          hout[((size_t)(b * (Lz + 2) + l0 + row + 1)) * 384 + c] = f2bf(y);
        } else {
          dotp += y * lwv[n];
        }
      }
      if constexpr (LAYER == 2) {
        #pragma unroll
        for (int off = 1; off < 16; off <<= 1) dotp += __shfl_xor(dotp, off);
        if (l15 == 0) s_dot[wc][row] = dotp;
      }
    }
  }
  if constexpr (LAYER == 2) {
    __syncthreads();
    if (tid < 128) {
      float dsum = lbias[0];
      #pragma unroll
      for (int w = 0; w < 4; ++w) dsum += s_dot[w][tid];
      dur[(size_t)b * Lz + l0 + tid] = fmaxf(dsum, 0.f);
    }
  }
}

extern "C" void kernel_launch(void* const* d_in, const int* in_sizes, int n_in,
                              void* d_out, int out_size, void* d_ws, size_t ws_size,
                              hipStream_t stream) {
  (void)in_sizes; (void)n_in; (void)out_size; (void)ws_size;
  const float* x   = (const float*)d_in[0];
  const int* tgt   = (const int*)d_in[1];
  const float* w1  = (const float*)d_in[3];
  const float* c1b = (const float*)d_in[4];
  const float* g1  = (const float*)d_in[5];
  const float* b1  = (const float*)d_in[6];
  const float* w2  = (const float*)d_in[7];
  const float* c2b = (const float*)d_in[8];
  const float* g2  = (const float*)d_in[9];
  const float* b2  = (const float*)d_in[10];
  const float* lw  = (const float*)d_in[11];
  const float* lb  = (const float*)d_in[12];

  float* out0 = (float*)d_out;
  float* dur  = out0 + (size_t)Bz * Mz * Dz;

  const size_t xbf_n = (size_t)Bz * (Lz + 2) * Dz;  // 12,607,488 bf16
  const size_t wt_n  = (size_t)KWz * Fz * Dz;       // 442,368 bf16
  u16* xbf = (u16*)d_ws;
  u16* h1  = xbf + xbf_n;
  u16* w1t = h1 + xbf_n;
  u16* w2t = w1t + wt_n;
  int* idxb = (int*)(w2t + wt_n);  // byte offset divisible by 4

  constexpr int CONV_BLKS = (Bz * Lz * Dz / 8) / 1024;   // 1536
  constexpr int PREP_BLKS = (2 * KWz * Fz * Dz + 2 * Bz * 2 * Dz + 1023) / 1024;
  k_pre<<<CONV_BLKS + PREP_BLKS + Bz, 1024, 0, stream>>>(x, xbf, w1, w2, w1t, w2t,
                                                         h1, tgt, idxb);
  k_conv<1><<<256, 512, 0, stream>>>(xbf, w1t, c1b, g1, b1, h1, nullptr, nullptr,
                                     nullptr);
  k_conv<2><<<256, 512, 0, stream>>>(h1, w2t, c2b, g2, b2, nullptr, lw, lb, dur);
  k_gather<<<2048, 256, 0, stream>>>(x, idxb, out0);
}

// Round 9
// 130.315 us; speedup vs baseline: 1.7057x; 1.3342x over previous
//
#include <hip/hip_runtime.h>

#define DEV __device__ __forceinline__

typedef unsigned short u16;
typedef __attribute__((ext_vector_type(8))) short bf16x8;   // 8 bf16 (4 VGPRs)
typedef __attribute__((ext_vector_type(8))) unsigned short u16x8;
typedef __attribute__((ext_vector_type(4))) float f32x4;

constexpr int Bz = 32, Lz = 1024, Dz = 384, Fz = 384, KWz = 3, Mz = 4096;
constexpr float EPS = 1e-5f;

DEV u16 f2bf(float f) {  // RNE f32 -> bf16
  unsigned u = __float_as_uint(f);
  u += 0x7fffu + ((u >> 16) & 1u);
  return (u16)(u >> 16);
}

typedef __attribute__((address_space(1))) const unsigned char ga_t;
typedef __attribute__((address_space(3))) unsigned char la_t;
DEV void gload16(const void* g, void* l) {
  // async global->LDS, 16B per lane; LDS dest is wave-uniform base + lane*16
  __builtin_amdgcn_global_load_lds((ga_t*)g, (la_t*)l, 16, 0, 0);
}

// ---------- prep: weight transpose+cvt, h1 halo zero, cumsum+search ---------
__global__ __launch_bounds__(1024) void k_pre(
    const float* __restrict__ w1, const float* __restrict__ w2,
    u16* __restrict__ w1t, u16* __restrict__ w2t, u16* __restrict__ h1,
    const int* __restrict__ tgt, int* __restrict__ idxb) {
  __shared__ int sc[Lz];
  constexpr int WT = KWz * Fz * Dz;                     // 442368
  constexpr int PREP_ELEMS = 2 * WT + Bz * 2 * Dz;      // 909312
  constexpr int PREP_BLKS = (PREP_ELEMS + 1023) / 1024; // 888
  const int tid = threadIdx.x;

  if (blockIdx.x < PREP_BLKS) {
    int gid = blockIdx.x * 1024 + tid;
    if (gid < WT) {
      int k = gid / (Fz * Dz), rem = gid % (Fz * Dz);
      int f = rem / Dz, d = rem % Dz;
      w1t[gid] = f2bf(w1[(f * Dz + d) * KWz + k]);
    } else if (gid < 2 * WT) {
      int g2 = gid - WT;
      int k = g2 / (Fz * Fz), rem = g2 % (Fz * Fz);
      int co = rem / Fz, ci = rem % Fz;
      w2t[g2] = f2bf(w2[(co * Fz + ci) * KWz + k]);
    } else if (gid < PREP_ELEMS) {
      int p = gid - 2 * WT;  // h1 halo rows
      int b = p / (2 * Dz), r = (p / Dz) & 1, d = p % Dz;
      size_t row = (size_t)b * (Lz + 2) + (r ? (Lz + 1) : 0);
      h1[row * Dz + d] = 0;
    }
    return;
  }
  // ---- cumsum + searchsorted(right) ----
  int b = blockIdx.x - PREP_BLKS;
  sc[tid] = tgt[b * Lz + tid];
  __syncthreads();
  for (int off = 1; off < Lz; off <<= 1) {
    int add = (tid >= off) ? sc[tid - off] : 0;
    __syncthreads();
    sc[tid] += add;
    __syncthreads();
  }
  int total = sc[Lz - 1];
  for (int t = tid; t < Mz; t += 1024) {
    int lo = 0, hi = Lz;
    while (lo < hi) {
      int mid = (lo + hi) >> 1;
      if (sc[mid] > t) hi = mid; else lo = mid + 1;
    }
    int iv = (t < total) ? (lo > Lz - 1 ? Lz - 1 : lo) : -1;
    idxb[b * Mz + t] = iv;
  }
}

// ------------------------------ gather rows ---------------------------------
__global__ void k_gather(const float* __restrict__ x, const int* __restrict__ idxb,
                         float* __restrict__ out) {
  int wid = (blockIdx.x * blockDim.x + threadIdx.x) >> 6;
  int lane = threadIdx.x & 63;
  int nw = (gridDim.x * blockDim.x) >> 6;
  for (int row = wid; row < Bz * Mz; row += nw) {
    int b = row >> 12;  // Mz = 4096
    int iv = idxb[row];
    float4* dst = reinterpret_cast<float4*>(out + (size_t)row * Dz);
    if (iv < 0) {
      float4 z = make_float4(0.f, 0.f, 0.f, 0.f);
      dst[lane] = z;
      if (lane < 32) dst[64 + lane] = z;
    } else {
      const float4* src =
          reinterpret_cast<const float4*>(x + ((size_t)b * Lz + iv) * Dz);
      dst[lane] = src[lane];
      if (lane < 32) dst[64 + lane] = src[64 + lane];
    }
  }
}

// --------- fused conv1d(K=3,'same') + LayerNorm + ReLU (+ final dot) --------
// R4's winning schedule: [128 rows]x[384 cols], 36 K-steps of 32, 8 waves
// (2x4), wave tile 64x96, triple-buffered LDS, counted vmcnt + raw s_barrier.
// LAYER1: A staged as f32 DIRECTLY from x via global_load_lds (no convert
// pre-pass); halo rows clamp-staged and zeroed on the register read; f32->bf16
// cvt in-VALU on the LDS->reg path (bit-identical to the old convert kernel).
// LAYER2: A staged bf16 from padded h1 (exact R4 path).
template <int LAYER>
__global__ __launch_bounds__(512, 2) void k_conv(
    const void* __restrict__ Asrc, // LAYER1: x f32 [B][1024][384]; L2: h1 bf16
    const u16* __restrict__ wt,    // [3][384 out][384 in] bf16
    const float* __restrict__ cbias,
    const float* __restrict__ lng, const float* __restrict__ lnb,
    u16* __restrict__ hout,        // LAYER==1: padded output buffer
    const float* __restrict__ lw, const float* __restrict__ lbias,
    float* __restrict__ dur)       // LAYER==2: [B*L]
{
  constexpr int ABYTES = (LAYER == 1) ? 16384 : 8192;  // A tile bytes per buf
  __shared__ __align__(16) unsigned char Ash[3][ABYTES];
  __shared__ __align__(16) u16 Bsh[3][384 * 32];       // 3 x 24KB
  __shared__ float s_sum[4][128], s_sq[4][128], s_dot[4][128];

  const int tid = threadIdx.x;
  const int lane = tid & 63, wave = tid >> 6;   // 8 waves
  const int wr = wave >> 2, wc = wave & 3;      // 2 x 4 wave grid
  const int l15 = lane & 15, lh = lane >> 4;
  const int b = blockIdx.x >> 3, l0 = (blockIdx.x & 7) << 7;

  // ---- B staging: 24 chunks of 1KB, wave w takes chunks w, w+8, w+16 ------
  int bgof[3], bldo[3];
  #pragma unroll
  for (int i = 0; i < 3; ++i) {
    int c = wave + 8 * i;
    int slot = c * 64 + lane, f = slot >> 2, q = slot & 3;
    int ks = q ^ ((f >> 1) & 3);             // XOR slot swizzle (involution)
    bgof[i] = f * 384 + ks * 8;
    bldo[i] = c * 512;
  }

  // ---- A staging descriptors ----
  // LAYER1 (f32): 16 chunks; chunk c covers rows c*8..c*8+7 (128B f32 rows),
  //   lane -> row = (c*64+lane)>>3, 16B slot q=(c*64+lane)&7; pair p=q>>1
  //   pre-swizzled source pair p^(row&3) so reg-read at pair (lh^(row&3)).
  // LAYER2 (bf16): 8 chunks, exact R4 mapping.
  const float* xb = (const float*)Asrc + (size_t)b * Lz * 384;   // LAYER1
  const u16* in_row =
      (const u16*)Asrc + ((size_t)(b * (Lz + 2) + l0)) * 384;    // LAYER2
  int a_row[2], a_gcol[2], a_ldsb[2];  // LAYER1 (i=0,1)
  int a_gof = 0, a_ldo = 0;            // LAYER2
  if constexpr (LAYER == 1) {
    #pragma unroll
    for (int i = 0; i < 2; ++i) {
      int c = wave + 8 * i;            // 0..15
      int s = c * 64 + lane;
      int row = s >> 3, q = s & 7, p = q >> 1, e = q & 1;
      int pp = p ^ (row & 3);
      a_row[i] = row;                  // tile row 0..127
      a_gcol[i] = pp * 8 + e * 4;      // float offset within 32-col window
      a_ldsb[i] = c * 1024;            // byte base of chunk in Ash
    }
  } else {
    int c = wave;
    int slot = c * 64 + lane, r = slot >> 2, q = slot & 3;
    int ks = q ^ ((r >> 1) & 3);
    a_gof = r * 384 + ks * 8;          // u16 offset
    a_ldo = c * 1024;                  // bytes (c*512 u16)
  }

  auto STAGE = [&](int kt, int buf) {
    int tap = kt / 12;
    int d0 = (kt - tap * 12) * 32;
    const u16* sb = wt + tap * (384 * 384) + d0;
    #pragma unroll
    for (int i = 0; i < 3; ++i) gload16(sb + bgof[i], &Bsh[buf][bldo[i]]);
    if constexpr (LAYER == 1) {
      #pragma unroll
      for (int i = 0; i < 2; ++i) {
        int grow = l0 + a_row[i] + tap - 1;
        grow = grow < 0 ? 0 : (grow > Lz - 1 ? Lz - 1 : grow);  // clamp stage
        gload16(xb + (size_t)grow * 384 + d0 + a_gcol[i],
                &Ash[buf][a_ldsb[i]]);
      }
    } else {
      gload16(in_row + tap * 384 + d0 + a_gof, &Ash[buf][a_ldo]);
    }
  };

  // ---- fragment read offsets ----
  int tr[4];                       // tile rows for A frags
  int aoff2[4];                    // LAYER2 u16 offsets
  #pragma unroll
  for (int m = 0; m < 4; ++m) {
    tr[m] = wr * 64 + m * 16 + l15;
    aoff2[m] = tr[m] * 32 + (lh ^ ((tr[m] >> 1) & 3)) * 8;
  }
  int boff[6];
  #pragma unroll
  for (int n = 0; n < 6; ++n) {
    int c = wc * 96 + n * 16 + l15;
    boff[n] = c * 32 + (lh ^ ((c >> 1) & 3)) * 8;
  }

  f32x4 acc[4][6] = {};

  STAGE(0, 0);
  STAGE(1, 1);
  int cur = 0;
  for (int kt = 0; kt < 36; ++kt) {
    // stage kt landed; stage kt+1 (5 or 4 loads/thread) stays in flight
    if constexpr (LAYER == 1) {
      if (kt < 35) asm volatile("s_waitcnt vmcnt(5)" ::: "memory");
      else         asm volatile("s_waitcnt vmcnt(0)" ::: "memory");
    } else {
      if (kt < 35) asm volatile("s_waitcnt vmcnt(4)" ::: "memory");
      else         asm volatile("s_waitcnt vmcnt(0)" ::: "memory");
    }
    __builtin_amdgcn_s_barrier();
    __builtin_amdgcn_sched_barrier(0);
    const int tap = kt / 12;
    bf16x8 av[4], bv[6];
    if constexpr (LAYER == 1) {
      const float* af = (const float*)Ash[cur];
      #pragma unroll
      for (int m = 0; m < 4; ++m) {
        int fidx = tr[m] * 32 + (lh ^ (tr[m] & 3)) * 8;
        float4 lo = *reinterpret_cast<const float4*>(af + fidx);
        float4 hi = *reinterpret_cast<const float4*>(af + fidx + 4);
        int grow = l0 + tr[m] + tap - 1;
        bool oob = (unsigned)grow > (unsigned)(Lz - 1);
        u16x8 f;
        f[0] = f2bf(lo.x); f[1] = f2bf(lo.y); f[2] = f2bf(lo.z); f[3] = f2bf(lo.w);
        f[4] = f2bf(hi.x); f[5] = f2bf(hi.y); f[6] = f2bf(hi.z); f[7] = f2bf(hi.w);
        if (oob) f = (u16x8)(unsigned short)0;
        av[m] = (bf16x8)f;
      }
    } else {
      const u16* au = (const u16*)Ash[cur];
      #pragma unroll
      for (int m = 0; m < 4; ++m)
        av[m] = *reinterpret_cast<const bf16x8*>(au + aoff2[m]);
    }
    #pragma unroll
    for (int n = 0; n < 6; ++n)
      bv[n] = *reinterpret_cast<const bf16x8*>(&Bsh[cur][boff[n]]);
    if (kt < 34) {
      int nb = cur + 2; if (nb >= 3) nb -= 3;
      STAGE(kt + 2, nb);  // buf last read at step kt-1; barrier-protected
    }
    #pragma unroll
    for (int m = 0; m < 4; ++m)
      #pragma unroll
      for (int n = 0; n < 6; ++n)
        acc[m][n] =
            __builtin_amdgcn_mfma_f32_16x16x32_bf16(av[m], bv[n], acc[m][n], 0, 0, 0);
    cur = (cur == 2) ? 0 : cur + 1;
  }

  // ---- epilogue: bias + LayerNorm(F) + ReLU, then store bf16 or dot(lw) ----
  __syncthreads();
  float gv[6], bvv[6], cbv[6], lwv[6];
  #pragma unroll
  for (int n = 0; n < 6; ++n) {
    int c = wc * 96 + n * 16 + l15;
    gv[n] = lng[c]; bvv[n] = lnb[c]; cbv[n] = cbias[c];
    lwv[n] = (LAYER == 2) ? lw[c] : 0.f;
  }
  #pragma unroll
  for (int m = 0; m < 4; ++m) {
    #pragma unroll
    for (int r = 0; r < 4; ++r) {
      float s = 0.f, q2 = 0.f;
      #pragma unroll
      for (int n = 0; n < 6; ++n) {
        float v = acc[m][n][r] + cbv[n];
        s += v; q2 += v * v;
      }
      #pragma unroll
      for (int off = 1; off < 16; off <<= 1) {
        s += __shfl_xor(s, off);
        q2 += __shfl_xor(q2, off);
      }
      if (l15 == 0) {
        int row = wr * 64 + m * 16 + lh * 4 + r;
        s_sum[wc][row] = s;
        s_sq[wc][row] = q2;
      }
    }
  }
  __syncthreads();
  #pragma unroll
  for (int m = 0; m < 4; ++m) {
    #pragma unroll
    for (int r = 0; r < 4; ++r) {
      int row = wr * 64 + m * 16 + lh * 4 + r;
      float S = 0.f, Q = 0.f;
      #pragma unroll
      for (int w = 0; w < 4; ++w) { S += s_sum[w][row]; Q += s_sq[w][row]; }
      float mean = S * (1.f / 384.f);
      float var = Q * (1.f / 384.f) - mean * mean;
      float rstd = rsqrtf(var + EPS);
      float dotp = 0.f;
      #pragma unroll
      for (int n = 0; n < 6; ++n) {
        float v = acc[m][n][r] + cbv[n];
        float y = fmaxf((v - mean) * rstd * gv[n] + bvv[n], 0.f);
        if constexpr (LAYER == 1) {
          int c = wc * 96 + n * 16 + l15;
          hout[((size_t)(b * (Lz + 2) + l0 + row + 1)) * 384 + c] = f2bf(y);
        } else {
          dotp += y * lwv[n];
        }
      }
      if constexpr (LAYER == 2) {
        #pragma unroll
        for (int off = 1; off < 16; off <<= 1) dotp += __shfl_xor(dotp, off);
        if (l15 == 0) s_dot[wc][row] = dotp;
      }
    }
  }
  if constexpr (LAYER == 2) {
    __syncthreads();
    if (tid < 128) {
      float dsum = lbias[0];
      #pragma unroll
      for (int w = 0; w < 4; ++w) dsum += s_dot[w][tid];
      dur[(size_t)b * Lz + l0 + tid] = fmaxf(dsum, 0.f);
    }
  }
}

extern "C" void kernel_launch(void* const* d_in, const int* in_sizes, int n_in,
                              void* d_out, int out_size, void* d_ws, size_t ws_size,
                              hipStream_t stream) {
  (void)in_sizes; (void)n_in; (void)out_size; (void)ws_size;
  const float* x   = (const float*)d_in[0];
  const int* tgt   = (const int*)d_in[1];
  const float* w1  = (const float*)d_in[3];
  const float* c1b = (const float*)d_in[4];
  const float* g1  = (const float*)d_in[5];
  const float* b1  = (const float*)d_in[6];
  const float* w2  = (const float*)d_in[7];
  const float* c2b = (const float*)d_in[8];
  const float* g2  = (const float*)d_in[9];
  const float* b2  = (const float*)d_in[10];
  const float* lw  = (const float*)d_in[11];
  const float* lb  = (const float*)d_in[12];

  float* out0 = (float*)d_out;
  float* dur  = out0 + (size_t)Bz * Mz * Dz;

  const size_t h1_n = (size_t)Bz * (Lz + 2) * Dz;  // 12,607,488 bf16
  const size_t wt_n = (size_t)KWz * Fz * Dz;       // 442,368 bf16
  u16* h1  = (u16*)d_ws;
  u16* w1t = h1 + h1_n;
  u16* w2t = w1t + wt_n;
  int* idxb = (int*)(w2t + wt_n);  // byte offset divisible by 4

  constexpr int PREP_BLKS =
      (2 * KWz * Fz * Dz + Bz * 2 * Dz + 1023) / 1024;  // 888
  k_pre<<<PREP_BLKS + Bz, 1024, 0, stream>>>(w1, w2, w1t, w2t, h1, tgt, idxb);
  k_conv<1><<<256, 512, 0, stream>>>(x, w1t, c1b, g1, b1, h1, nullptr, nullptr,
                                     nullptr);
  k_conv<2><<<256, 512, 0, stream>>>(h1, w2t, c2b, g2, b2, nullptr, lw, lb, dur);
  k_gather<<<2048, 256, 0, stream>>>(x, idxb, out0);
}

// Round 10
// 122.481 us; speedup vs baseline: 1.8148x; 1.0640x over previous
//
#include <hip/hip_runtime.h>

#define DEV __device__ __forceinline__

typedef unsigned short u16;
typedef __attribute__((ext_vector_type(8))) short bf16x8;   // 8 bf16 (4 VGPRs)
typedef __attribute__((ext_vector_type(8))) unsigned short u16x8;
typedef __attribute__((ext_vector_type(4))) float f32x4;

constexpr int Bz = 32, Lz = 1024, Dz = 384, Fz = 384, KWz = 3, Mz = 4096;
constexpr float EPS = 1e-5f;

DEV u16 f2bf(float f) {  // RNE f32 -> bf16
  unsigned u = __float_as_uint(f);
  u += 0x7fffu + ((u >> 16) & 1u);
  return (u16)(u >> 16);
}

typedef __attribute__((address_space(1))) const unsigned char ga_t;
typedef __attribute__((address_space(3))) unsigned char la_t;
DEV void gload16(const void* g, void* l) {
  // async global->LDS, 16B per lane; LDS dest is wave-uniform base + lane*16
  __builtin_amdgcn_global_load_lds((ga_t*)g, (la_t*)l, 16, 0, 0);
}

#define WAITV(n) asm volatile("s_waitcnt vmcnt(" #n ")" ::: "memory")

// ---------- prep: weight transpose+cvt, h1 halo zero, cumsum+search ---------
__global__ __launch_bounds__(1024) void k_pre(
    const float* __restrict__ w1, const float* __restrict__ w2,
    u16* __restrict__ w1t, u16* __restrict__ w2t, u16* __restrict__ h1,
    const int* __restrict__ tgt, int* __restrict__ idxb) {
  __shared__ int sc[Lz];
  constexpr int WT = KWz * Fz * Dz;                     // 442368
  constexpr int PREP_ELEMS = 2 * WT + Bz * 2 * Dz;      // 909312
  constexpr int PREP_BLKS = (PREP_ELEMS + 1023) / 1024; // 888
  const int tid = threadIdx.x;

  if (blockIdx.x < PREP_BLKS) {
    int gid = blockIdx.x * 1024 + tid;
    if (gid < WT) {
      int k = gid / (Fz * Dz), rem = gid % (Fz * Dz);
      int f = rem / Dz, d = rem % Dz;
      w1t[gid] = f2bf(w1[(f * Dz + d) * KWz + k]);
    } else if (gid < 2 * WT) {
      int g2 = gid - WT;
      int k = g2 / (Fz * Fz), rem = g2 % (Fz * Fz);
      int co = rem / Fz, ci = rem % Fz;
      w2t[g2] = f2bf(w2[(co * Fz + ci) * KWz + k]);
    } else if (gid < PREP_ELEMS) {
      int p = gid - 2 * WT;  // h1 halo rows
      int b = p / (2 * Dz), r = (p / Dz) & 1, d = p % Dz;
      size_t row = (size_t)b * (Lz + 2) + (r ? (Lz + 1) : 0);
      h1[row * Dz + d] = 0;
    }
    return;
  }
  // ---- cumsum + searchsorted(right) ----
  int b = blockIdx.x - PREP_BLKS;
  sc[tid] = tgt[b * Lz + tid];
  __syncthreads();
  for (int off = 1; off < Lz; off <<= 1) {
    int add = (tid >= off) ? sc[tid - off] : 0;
    __syncthreads();
    sc[tid] += add;
    __syncthreads();
  }
  int total = sc[Lz - 1];
  for (int t = tid; t < Mz; t += 1024) {
    int lo = 0, hi = Lz;
    while (lo < hi) {
      int mid = (lo + hi) >> 1;
      if (sc[mid] > t) hi = mid; else lo = mid + 1;
    }
    int iv = (t < total) ? (lo > Lz - 1 ? Lz - 1 : lo) : -1;
    idxb[b * Mz + t] = iv;
  }
}

// ------------------------------ gather rows ---------------------------------
__global__ void k_gather(const float* __restrict__ x, const int* __restrict__ idxb,
                         float* __restrict__ out) {
  int wid = (blockIdx.x * blockDim.x + threadIdx.x) >> 6;
  int lane = threadIdx.x & 63;
  int nw = (gridDim.x * blockDim.x) >> 6;
  for (int row = wid; row < Bz * Mz; row += nw) {
    int b = row >> 12;  // Mz = 4096
    int iv = idxb[row];
    float4* dst = reinterpret_cast<float4*>(out + (size_t)row * Dz);
    if (iv < 0) {
      float4 z = make_float4(0.f, 0.f, 0.f, 0.f);
      dst[lane] = z;
      if (lane < 32) dst[64 + lane] = z;
    } else {
      const float4* src =
          reinterpret_cast<const float4*>(x + ((size_t)b * Lz + iv) * Dz);
      dst[lane] = src[lane];
      if (lane < 32) dst[64 + lane] = src[64 + lane];
    }
  }
}

// --------- fused conv1d(K=3,'same') + LayerNorm + ReLU (+ final dot) --------
// Taps-inner K-order: kt = 3w + t; window w = 32 k-cols shared by 3 taps via
// row-shifted LDS reads. A in LDS as bf16 granule-major [4 g][256 r] (16KB),
// conflict-free b128 frags. LAYER1: A reg-staged (coalesced f32 loads -> f2bf
// -> 2x ds_write_b128), 2 bufs. LAYER2: A via global_load_lds, 3 bufs.
// B: 3-buf global_load_lds (B(kt)->Bsh[kt%3]). Counted vmcnt + raw s_barrier;
// lgkmcnt(0) before each barrier fences cross-wave ds_writes.
template <int LAYER>
__global__ __launch_bounds__(512, 2) void k_conv(
    const void* __restrict__ Asrc, // LAYER1: x f32 [B][1024][384]; L2: h1 bf16
    const u16* __restrict__ wt,    // [3][384 out][384 in] bf16
    const float* __restrict__ cbias,
    const float* __restrict__ lng, const float* __restrict__ lnb,
    u16* __restrict__ hout,        // LAYER==1: padded output buffer
    const float* __restrict__ lw, const float* __restrict__ lbias,
    float* __restrict__ dur)       // LAYER==2: [B*L]
{
  constexpr int ABUFS = (LAYER == 1) ? 2 : 3;
  __shared__ __align__(16) u16 Ash[ABUFS][8192];   // 16KB per buf
  __shared__ __align__(16) u16 Bsh[3][384 * 32];   // 3 x 24KB
  __shared__ float s_sum[4][128], s_sq[4][128], s_dot[4][128];

  const int tid = threadIdx.x;
  const int lane = tid & 63, wave = tid >> 6;   // 8 waves
  const int wr = wave >> 2, wc = wave & 3;      // 2 x 4 wave grid
  const int l15 = lane & 15, lh = lane >> 4;
  const int b = blockIdx.x >> 3, l0 = (blockIdx.x & 7) << 7;
  const bf16x8 zfrag = {0, 0, 0, 0, 0, 0, 0, 0};

  // ---- B staging: 24 chunks of 1KB, wave w takes chunks w, w+8, w+16 ------
  int bgof[3], bldo[3];
  #pragma unroll
  for (int i = 0; i < 3; ++i) {
    int c = wave + 8 * i;
    int slot = c * 64 + lane, f = slot >> 2, q = slot & 3;
    int ks = q ^ ((f >> 1) & 3);             // XOR slot swizzle (involution)
    bgof[i] = f * 384 + ks * 8;
    bldo[i] = c * 512;
  }
  auto STAGE_B = [&](int kt) {               // B(kt) -> Bsh[kt%3]
    int tap = kt % 3, dw = kt / 3;
    const u16* sb = wt + tap * (384 * 384) + dw * 32;
    u16* dst = Bsh[tap];
    #pragma unroll
    for (int i = 0; i < 3; ++i) gload16(sb + bgof[i], dst + bldo[i]);
  };

  // ---- A staging state ----
  const float* arow_ptr = nullptr;           // LAYER1
  const u16* a2src[2] = {nullptr, nullptr};  // LAYER2
  int a2ldo[2] = {0, 0};
  float4 ar0, ar1, ar2, ar3;
  if constexpr (LAYER == 1) {
    // thread t owns slots {t, t+512}: (g1, r1) and (g1+2, r1), r1 = t&255
    int r1 = tid & 255, g1 = tid >> 8;
    int grow = l0 - 1 + r1;
    if (grow > l0 + 135) grow = l0 + 135;    // rows >135 never read: dedupe
    if (grow < 0) grow = 0;
    if (grow > Lz - 1) grow = Lz - 1;
    arow_ptr = (const float*)Asrc + (size_t)b * Lz * 384 + (size_t)grow * 384 +
               g1 * 8;
  } else {
    #pragma unroll
    for (int i = 0; i < 2; ++i) {
      int c = wave + 8 * i;                  // 16 chunks of 1KB
      int s = c * 64 + lane, g = s >> 8, r = s & 255;
      int p = l0 + r;                        // padded row index
      if (p > l0 + 135) p = l0 + 135;
      if (p > Lz + 1) p = Lz + 1;
      a2src[i] = (const u16*)Asrc + (size_t)b * (Lz + 2) * 384 +
                 (size_t)p * 384 + g * 8;
      a2ldo[i] = c * 512;
    }
  }
  auto AISSUE = [&](int w) {                 // LAYER1: load window-w regs
    const float* p = arow_ptr + w * 32;
    ar0 = *reinterpret_cast<const float4*>(p);
    ar1 = *reinterpret_cast<const float4*>(p + 4);
    ar2 = *reinterpret_cast<const float4*>(p + 16);
    ar3 = *reinterpret_cast<const float4*>(p + 20);
  };
  auto ADSW = [&](int wbuf) {                // LAYER1: regs -> LDS bf16
    u16x8 h0, h1;
    h0[0] = f2bf(ar0.x); h0[1] = f2bf(ar0.y); h0[2] = f2bf(ar0.z); h0[3] = f2bf(ar0.w);
    h0[4] = f2bf(ar1.x); h0[5] = f2bf(ar1.y); h0[6] = f2bf(ar1.z); h0[7] = f2bf(ar1.w);
    h1[0] = f2bf(ar2.x); h1[1] = f2bf(ar2.y); h1[2] = f2bf(ar2.z); h1[3] = f2bf(ar2.w);
    h1[4] = f2bf(ar3.x); h1[5] = f2bf(ar3.y); h1[6] = f2bf(ar3.z); h1[7] = f2bf(ar3.w);
    *reinterpret_cast<u16x8*>(&Ash[wbuf][tid * 8]) = h0;
    *reinterpret_cast<u16x8*>(&Ash[wbuf][(tid + 512) * 8]) = h1;
  };
  auto STAGE_A2 = [&](int w, int buf) {      // LAYER2: async A window stage
    #pragma unroll
    for (int i = 0; i < 2; ++i) gload16(a2src[i] + w * 32, &Ash[buf][a2ldo[i]]);
  };

  // ---- fragment offsets ----
  int tr[4], boff[6];
  #pragma unroll
  for (int m = 0; m < 4; ++m) tr[m] = wr * 64 + m * 16 + l15;
  #pragma unroll
  for (int n = 0; n < 6; ++n) {
    int c = wc * 96 + n * 16 + l15;
    boff[n] = c * 32 + (lh ^ ((c >> 1) & 3)) * 8;
  }

  f32x4 acc[4][6] = {};

  // ---- prologue ----
  if constexpr (LAYER == 1) {
    AISSUE(0);
    WAITV(0);
    ADSW(0);
    AISSUE(1);
    __builtin_amdgcn_sched_barrier(0);  // pin: aregs(1) issued before B(0),B(1)
    STAGE_B(0);
    STAGE_B(1);
  } else {
    STAGE_A2(0, 0);
    STAGE_B(0);
    STAGE_A2(1, 1);
    STAGE_B(1);
  }

#define PHASE(T)                                                               \
  {                                                                            \
    if constexpr ((T) == 0) {                                                  \
      if constexpr (LAYER == 2) {                                              \
        if (w == 0) { WAITV(5); } else { WAITV(3); }                           \
      } else { WAITV(3); }                                                     \
    } else if constexpr ((T) == 1) {                                           \
      if (w <= 9) {                                                            \
        if constexpr (LAYER == 1) { WAITV(7); } else { WAITV(5); }             \
      } else { WAITV(3); }                                                     \
    } else {                                                                   \
      if (w <= 9) {                                                            \
        if constexpr (LAYER == 1) { WAITV(7); } else { WAITV(5); }             \
      } else if (w == 10) { WAITV(3); } else { WAITV(0); }                     \
    }                                                                          \
    asm volatile("s_waitcnt lgkmcnt(0)" ::: "memory");                         \
    __builtin_amdgcn_s_barrier();                                              \
    __builtin_amdgcn_sched_barrier(0);                                         \
    if constexpr (LAYER == 1 && (T) == 0) {                                    \
      if (w <= 10) ADSW((w + 1) & 1);                                          \
    }                                                                          \
    const int abuf_ = (LAYER == 1) ? (w & 1) : (w % 3);                        \
    bf16x8 av[4], bv[6];                                                       \
    _Pragma("unroll")                                                          \
    for (int m = 0; m < 4; ++m) {                                              \
      av[m] = *reinterpret_cast<const bf16x8*>(                                \
          &Ash[abuf_][(lh * 256 + tr[m] + (T)) * 8]);                          \
      if constexpr (LAYER == 1 && (T) != 1) {                                  \
        int gr = l0 + tr[m] + (T) - 1;                                         \
        if ((unsigned)gr > (unsigned)(Lz - 1)) av[m] = zfrag;                  \
      }                                                                        \
    }                                                                          \
    _Pragma("unroll")                                                          \
    for (int n = 0; n < 6; ++n)                                                \
      bv[n] = *reinterpret_cast<const bf16x8*>(&Bsh[(T)][boff[n]]);            \
    __builtin_amdgcn_sched_barrier(0);                                         \
    { int kt2_ = 3 * w + (T) + 2; if (kt2_ <= 35) STAGE_B(kt2_); }             \
    __builtin_amdgcn_sched_barrier(0);                                         \
    if constexpr ((T) == 0) {                                                  \
      if (w <= 9) {                                                            \
        if constexpr (LAYER == 1) { AISSUE(w + 2); }                           \
        else { STAGE_A2(w + 2, (w + 2) % 3); }                                 \
      }                                                                        \
    }                                                                          \
    __builtin_amdgcn_sched_barrier(0);                                         \
    _Pragma("unroll")                                                          \
    for (int m = 0; m < 4; ++m)                                                \
      _Pragma("unroll")                                                        \
      for (int n = 0; n < 6; ++n)                                              \
        acc[m][n] = __builtin_amdgcn_mfma_f32_16x16x32_bf16(av[m], bv[n],      \
                                                            acc[m][n], 0, 0, 0);\
  }

  for (int w = 0; w < 12; ++w) {
    PHASE(0)
    PHASE(1)
    PHASE(2)
  }
#undef PHASE

  // ---- epilogue: bias + LayerNorm(F) + ReLU, then store bf16 or dot(lw) ----
  __syncthreads();
  float gv[6], bvv[6], cbv[6], lwv[6];
  #pragma unroll
  for (int n = 0; n < 6; ++n) {
    int c = wc * 96 + n * 16 + l15;
    gv[n] = lng[c]; bvv[n] = lnb[c]; cbv[n] = cbias[c];
    lwv[n] = (LAYER == 2) ? lw[c] : 0.f;
  }
  #pragma unroll
  for (int m = 0; m < 4; ++m) {
    #pragma unroll
    for (int r = 0; r < 4; ++r) {
      float s = 0.f, q2 = 0.f;
      #pragma unroll
      for (int n = 0; n < 6; ++n) {
        float v = acc[m][n][r] + cbv[n];
        s += v; q2 += v * v;
      }
      #pragma unroll
      for (int off = 1; off < 16; off <<= 1) {
        s += __shfl_xor(s, off);
        q2 += __shfl_xor(q2, off);
      }
      if (l15 == 0) {
        int row = wr * 64 + m * 16 + lh * 4 + r;
        s_sum[wc][row] = s;
        s_sq[wc][row] = q2;
      }
    }
  }
  __syncthreads();
  #pragma unroll
  for (int m = 0; m < 4; ++m) {
    #pragma unroll
    for (int r = 0; r < 4; ++r) {
      int row = wr * 64 + m * 16 + lh * 4 + r;
      float S = 0.f, Q = 0.f;
      #pragma unroll
      for (int w = 0; w < 4; ++w) { S += s_sum[w][row]; Q += s_sq[w][row]; }
      float mean = S * (1.f / 384.f);
      float var = Q * (1.f / 384.f) - mean * mean;
      float rstd = rsqrtf(var + EPS);
      float dotp = 0.f;
      #pragma unroll
      for (int n = 0; n < 6; ++n) {
        float v = acc[m][n][r] + cbv[n];
        float y = fmaxf((v - mean) * rstd * gv[n] + bvv[n], 0.f);
        if constexpr (LAYER == 1) {
          int c = wc * 96 + n * 16 + l15;
          hout[((size_t)(b * (Lz + 2) + l0 + row + 1)) * 384 + c] = f2bf(y);
        } else {
          dotp += y * lwv[n];
        }
      }
      if constexpr (LAYER == 2) {
        #pragma unroll
        for (int off = 1; off < 16; off <<= 1) dotp += __shfl_xor(dotp, off);
        if (l15 == 0) s_dot[wc][row] = dotp;
      }
    }
  }
  if constexpr (LAYER == 2) {
    __syncthreads();
    if (tid < 128) {
      float dsum = lbias[0];
      #pragma unroll
      for (int w = 0; w < 4; ++w) dsum += s_dot[w][tid];
      dur[(size_t)b * Lz + l0 + tid] = fmaxf(dsum, 0.f);
    }
  }
}

extern "C" void kernel_launch(void* const* d_in, const int* in_sizes, int n_in,
                              void* d_out, int out_size, void* d_ws, size_t ws_size,
                              hipStream_t stream) {
  (void)in_sizes; (void)n_in; (void)out_size; (void)ws_size;
  const float* x   = (const float*)d_in[0];
  const int* tgt   = (const int*)d_in[1];
  const float* w1  = (const float*)d_in[3];
  const float* c1b = (const float*)d_in[4];
  const float* g1  = (const float*)d_in[5];
  const float* b1  = (const float*)d_in[6];
  const float* w2  = (const float*)d_in[7];
  const float* c2b = (const float*)d_in[8];
  const float* g2  = (const float*)d_in[9];
  const float* b2  = (const float*)d_in[10];
  const float* lw  = (const float*)d_in[11];
  const float* lb  = (const float*)d_in[12];

  float* out0 = (float*)d_out;
  float* dur  = out0 + (size_t)Bz * Mz * Dz;

  const size_t h1_n = (size_t)Bz * (Lz + 2) * Dz;  // 12,607,488 bf16
  const size_t wt_n = (size_t)KWz * Fz * Dz;       // 442,368 bf16
  u16* h1  = (u16*)d_ws;
  u16* w1t = h1 + h1_n;
  u16* w2t = w1t + wt_n;
  int* idxb = (int*)(w2t + wt_n);  // byte offset divisible by 4

  constexpr int PREP_BLKS =
      (2 * KWz * Fz * Dz + Bz * 2 * Dz + 1023) / 1024;  // 888
  k_pre<<<PREP_BLKS + Bz, 1024, 0, stream>>>(w1, w2, w1t, w2t, h1, tgt, idxb);
  k_conv<1><<<256, 512, 0, stream>>>(x, w1t, c1b, g1, b1, h1, nullptr, nullptr,
                                     nullptr);
  k_conv<2><<<256, 512, 0, stream>>>(h1, w2t, c2b, g2, b2, nullptr, lw, lb, dur);
  k_gather<<<2048, 256, 0, stream>>>(x, idxb, out0);
}